// Round 1
// baseline (534.416 us; speedup 1.0000x reference)
//
#include <hip/hip_runtime.h>
#include <math.h>
#include <cstddef>

#define BB 2
#define SS 2048
#define HH 16
#define DD 64

// One wave (64 lanes) per (b, h, t); lane = head dim d.
// Backward scan s = t-1 .. 0 with running C = sum softplus(score).
// att = exp(log_sigmoid(score) - C) = exp((x - softplus(x)) - C).
// Remaining stick mass after C is exp(-C): early-exit at C > 30 is exact to ~1e-13.
__global__ __launch_bounds__(256) void sb_attn_kernel(const float* __restrict__ qkv,
                                                      float* __restrict__ out) {
    const int lane = threadIdx.x & 63;
    const int wave = threadIdx.x >> 6;
    const int w = blockIdx.x * 4 + wave;        // w = (b*HH + h)*SS + t
    const int t  = w & (SS - 1);
    const int bh = w >> 11;                      // SS = 2048 = 2^11
    const int h  = bh & (HH - 1);
    const int b  = bh >> 4;                      // HH = 16 = 2^4

    const float scale = 1.5f / 8.0f;             // 1.5/sqrt(64)
    const size_t row_stride = (size_t)3 * HH * DD;   // floats per (b,s) row
    const float* base = qkv + (size_t)b * SS * row_stride + (size_t)h * DD;
    const float* kp = base + HH * DD;            // k plane (idx 1)
    const float* vp = base + 2 * HH * DD;        // v plane (idx 2)

    const float qv = base[(size_t)t * row_stride + lane] * scale;

    float out_acc = 0.f;
    float att_sum = 0.f;
    float C = 0.f;

    for (int s = t - 1; s >= 0; --s) {
        float kv = kp[(size_t)s * row_stride + lane];
        float p = qv * kv;
        // 64-lane butterfly reduce -> every lane holds the score
        #pragma unroll
        for (int off = 32; off > 0; off >>= 1)
            p += __shfl_xor(p, off, 64);
        const float x = p;
        // stable softplus(x) = max(x,0) + log1p(exp(-|x|))
        const float sp = fmaxf(x, 0.f) + log1pf(__expf(-fabsf(x)));
        const float att = __expf((x - sp) - C);   // exp(log_sigmoid(x) - C)
        const float vv = vp[(size_t)s * row_stride + lane];
        out_acc = fmaf(att, vv, out_acc);
        att_sum += att;
        C += sp;
        if (C > 30.f) break;                      // remaining mass = exp(-C) < 1e-13
    }

    const float rem = 1.f - att_sum;
    const float vt = vp[(size_t)t * row_stride + lane];
    out[(((size_t)b * SS + t) * HH + h) * DD + lane] = fmaf(rem, vt, out_acc);
}

extern "C" void kernel_launch(void* const* d_in, const int* in_sizes, int n_in,
                              void* d_out, int out_size, void* d_ws, size_t ws_size,
                              hipStream_t stream) {
    const float* qkv = (const float*)d_in[0];
    float* out = (float*)d_out;
    const int total_waves = BB * HH * SS;        // 65536
    const int blocks = total_waves / 4;          // 4 waves per 256-thread block
    sb_attn_kernel<<<blocks, 256, 0, stream>>>(qkv, out);
}

// Round 2
// 162.314 us; speedup vs baseline: 3.2925x; 3.2925x over previous
//
#include <hip/hip_runtime.h>
#include <math.h>
#include <cstddef>

#define BB 2
#define SSEQ 2048
#define HH 16
#define DD 64
#define ROW 3072              // floats per (b,s) row = 3*H*D
#define TT 64                 // t-tile
#define SCH 64                // s-chunk
#define STRD 68               // padded LDS leading dim (16B-aligned, low-conflict)

// Block = 256 threads (4 waves) handles t in [T0, T0+64) for one (b,h).
// Backward s-chunks of 64: stage K^T,V in LDS; score tile via fp32 4x4
// outer-product; per-row suffix scan of softplus via shuffles (lane = s);
// att = exp(x - sp - rev_excl - C_carry) written in place; att*V via second
// 4x4 outer-product into register accumulator. Early exit when all rows'
// C > 30 (residual mass exp(-30) ~ 1e-13).
__global__ __launch_bounds__(256, 2) void sb_attn_tiled(const float* __restrict__ qkv,
                                                        float* __restrict__ out) {
    __shared__ float QT[DD][STRD];   // Q^T[d][t], pre-scaled
    __shared__ float KT[DD][STRD];   // K^T[d][s]
    __shared__ float Vs[SCH][DD];    // V[s][d]
    __shared__ float Sc[TT][STRD];   // scores -> att (in place)
    __shared__ float asum[TT];
    __shared__ float Ccar[TT];
    __shared__ int done_cnt;

    const int tid = threadIdx.x;
    const int w = tid >> 6;
    const int lane = tid & 63;
    const int bh = blockIdx.x >> 5;
    const int h = bh & (HH - 1);
    const int b = bh >> 4;
    const int T0 = (blockIdx.x & 31) * TT;

    const float scale = 0.1875f;     // 1.5/sqrt(64)
    const float* qb = qkv + (size_t)b * SSEQ * ROW + h * DD;  // q plane
    const float* kb = qb + HH * DD;                            // k plane
    const float* vb = qb + 2 * HH * DD;                        // v plane

    // ---- stage Q^T (once) : wave reads 4 q rows coalesced, writes b128 along t
    #pragma unroll
    for (int g = 0; g < 4; ++g) {
        const int tb = w * 16 + g * 4;
        float q0 = qb[(size_t)(T0 + tb + 0) * ROW + lane] * scale;
        float q1 = qb[(size_t)(T0 + tb + 1) * ROW + lane] * scale;
        float q2 = qb[(size_t)(T0 + tb + 2) * ROW + lane] * scale;
        float q3 = qb[(size_t)(T0 + tb + 3) * ROW + lane] * scale;
        float4 t4 = make_float4(q0, q1, q2, q3);
        *(float4*)&QT[lane][tb] = t4;
    }
    if (tid < TT) { asum[tid] = 0.f; Ccar[tid] = 0.f; }

    const int t0 = (tid >> 4) << 2;      // PV/QK row group (matches scan wave ownership)
    const int s0 = (tid & 15) << 2;      // QK col group / PV d group
    float o[4][4] = {};

    for (int S0 = T0; S0 >= 0; S0 -= SCH) {
        __syncthreads();                 // prev PV done before overwriting KT/Vs/Sc

        // ---- stage K^T chunk: transposed b128 writes
        if (tid == 0) done_cnt = 0;
        #pragma unroll
        for (int g = 0; g < 4; ++g) {
            const int sb = w * 16 + g * 4;
            float k0 = kb[(size_t)(S0 + sb + 0) * ROW + lane];
            float k1 = kb[(size_t)(S0 + sb + 1) * ROW + lane];
            float k2 = kb[(size_t)(S0 + sb + 2) * ROW + lane];
            float k3 = kb[(size_t)(S0 + sb + 3) * ROW + lane];
            float4 t4 = make_float4(k0, k1, k2, k3);
            *(float4*)&KT[lane][sb] = t4;
        }
        // ---- stage V chunk (natural layout)
        #pragma unroll
        for (int j = 0; j < 16; ++j) {
            const int s = w * 16 + j;
            Vs[s][lane] = vb[(size_t)(S0 + s) * ROW + lane];
        }
        __syncthreads();

        // ---- QK^T: 64x64 tile, 4x4 per thread
        {
            float acc[4][4] = {};
            #pragma unroll 4
            for (int d = 0; d < DD; ++d) {
                float4 q4 = *(const float4*)&QT[d][t0];
                float4 k4 = *(const float4*)&KT[d][s0];
                acc[0][0] = fmaf(q4.x, k4.x, acc[0][0]);
                acc[0][1] = fmaf(q4.x, k4.y, acc[0][1]);
                acc[0][2] = fmaf(q4.x, k4.z, acc[0][2]);
                acc[0][3] = fmaf(q4.x, k4.w, acc[0][3]);
                acc[1][0] = fmaf(q4.y, k4.x, acc[1][0]);
                acc[1][1] = fmaf(q4.y, k4.y, acc[1][1]);
                acc[1][2] = fmaf(q4.y, k4.z, acc[1][2]);
                acc[1][3] = fmaf(q4.y, k4.w, acc[1][3]);
                acc[2][0] = fmaf(q4.z, k4.x, acc[2][0]);
                acc[2][1] = fmaf(q4.z, k4.y, acc[2][1]);
                acc[2][2] = fmaf(q4.z, k4.z, acc[2][2]);
                acc[2][3] = fmaf(q4.z, k4.w, acc[2][3]);
                acc[3][0] = fmaf(q4.w, k4.x, acc[3][0]);
                acc[3][1] = fmaf(q4.w, k4.y, acc[3][1]);
                acc[3][2] = fmaf(q4.w, k4.z, acc[3][2]);
                acc[3][3] = fmaf(q4.w, k4.w, acc[3][3]);
            }
            #pragma unroll
            for (int i = 0; i < 4; ++i)
                *(float4*)&Sc[t0 + i][s0] = make_float4(acc[i][0], acc[i][1], acc[i][2], acc[i][3]);
        }
        __syncthreads();

        // ---- per-row suffix scan (lane = s), att in place
        #pragma unroll
        for (int j = 0; j < 16; ++j) {
            const int t = w * 16 + j;
            const int tG = T0 + t;
            const float x = Sc[t][lane];
            const bool valid = (S0 + lane) < tG;
            float sp = valid ? (fmaxf(x, 0.f) + log1pf(__expf(-fabsf(x)))) : 0.f;
            float v = sp;
            #pragma unroll
            for (int off = 1; off < 64; off <<= 1) {
                float ov = __shfl_down(v, off, 64);
                if (lane + off < 64) v += ov;
            }
            const float rev = v - sp;            // sum over s' > lane
            const float ctot = __shfl(v, 0, 64); // chunk softplus total
            const float C = Ccar[t];
            const float att = valid ? __expf(x - sp - rev - C) : 0.f;
            Sc[t][lane] = att;
            float a = att;
            #pragma unroll
            for (int off = 32; off > 0; off >>= 1) a += __shfl_xor(a, off, 64);
            if (lane == 0) {
                asum[t] += a;
                const float Cn = C + ctot;
                Ccar[t] = Cn;
                if (Cn > 30.f) atomicAdd(&done_cnt, 1);
            }
        }
        __syncthreads();
        const bool alldone = (done_cnt == TT);

        // ---- att * V: 4x4 per thread, accumulate across chunks
        #pragma unroll 4
        for (int s = 0; s < SCH; s += 4) {
            float4 a0 = *(const float4*)&Sc[t0 + 0][s];
            float4 a1 = *(const float4*)&Sc[t0 + 1][s];
            float4 a2 = *(const float4*)&Sc[t0 + 2][s];
            float4 a3 = *(const float4*)&Sc[t0 + 3][s];
            #pragma unroll
            for (int k = 0; k < 4; ++k) {
                float4 vv = *(const float4*)&Vs[s + k][s0];
                const float av0 = (&a0.x)[k], av1 = (&a1.x)[k], av2 = (&a2.x)[k], av3 = (&a3.x)[k];
                o[0][0] = fmaf(av0, vv.x, o[0][0]);
                o[0][1] = fmaf(av0, vv.y, o[0][1]);
                o[0][2] = fmaf(av0, vv.z, o[0][2]);
                o[0][3] = fmaf(av0, vv.w, o[0][3]);
                o[1][0] = fmaf(av1, vv.x, o[1][0]);
                o[1][1] = fmaf(av1, vv.y, o[1][1]);
                o[1][2] = fmaf(av1, vv.z, o[1][2]);
                o[1][3] = fmaf(av1, vv.w, o[1][3]);
                o[2][0] = fmaf(av2, vv.x, o[2][0]);
                o[2][1] = fmaf(av2, vv.y, o[2][1]);
                o[2][2] = fmaf(av2, vv.z, o[2][2]);
                o[2][3] = fmaf(av2, vv.w, o[2][3]);
                o[3][0] = fmaf(av3, vv.x, o[3][0]);
                o[3][1] = fmaf(av3, vv.y, o[3][1]);
                o[3][2] = fmaf(av3, vv.z, o[3][2]);
                o[3][3] = fmaf(av3, vv.w, o[3][3]);
            }
        }
        if (alldone) break;
    }

    // ---- epilogue: += rem * v_t, store
    #pragma unroll
    for (int i = 0; i < 4; ++i) {
        const int tG = T0 + t0 + i;
        const float rem = 1.f - asum[t0 + i];
        float4 vv = *(const float4*)&vb[(size_t)tG * ROW + s0];
        float4 r;
        r.x = fmaf(rem, vv.x, o[i][0]);
        r.y = fmaf(rem, vv.y, o[i][1]);
        r.z = fmaf(rem, vv.z, o[i][2]);
        r.w = fmaf(rem, vv.w, o[i][3]);
        *(float4*)&out[(((size_t)b * SSEQ + tG) * HH + h) * DD + s0] = r;
    }
}

extern "C" void kernel_launch(void* const* d_in, const int* in_sizes, int n_in,
                              void* d_out, int out_size, void* d_ws, size_t ws_size,
                              hipStream_t stream) {
    const float* qkv = (const float*)d_in[0];
    float* out = (float*)d_out;
    const int blocks = BB * HH * (SSEQ / TT);   // 1024
    sb_attn_tiled<<<blocks, 256, 0, stream>>>(qkv, out);
}

// Round 4
// 140.277 us; speedup vs baseline: 3.8097x; 1.1571x over previous
//
#include <hip/hip_runtime.h>
#include <math.h>
#include <cstddef>

#define BB 2
#define SSEQ 2048
#define HH 16
#define DD 64
#define ROW 3072              // floats per (b,s) row = 3*H*D
#define TT 64                 // t-tile per block
#define SCH 64                // s-chunk

#define QK_STR 72             // bf16 elems/row for Q/K planes (144 B, 16B-aligned rows)
#define VT_STR 68             // bf16 elems/row for V^T (136 B, 8B-aligned rows)
#define SC_STR 68             // fp32 elems/row for scores (272 B); P (bf16) overlays, stride 136

typedef __attribute__((ext_vector_type(8))) short short8;
typedef __attribute__((ext_vector_type(4))) short short4v;
typedef __attribute__((ext_vector_type(4))) float floatx4;

__device__ inline short bf16_rn(float f) {
    unsigned u = __float_as_uint(f);
    return (short)((u + 0x8000u) >> 16);
}
struct bf2 { short h, l; };
// f ~= hi + lo, each bf16; captures ~16 mantissa bits across the pair
__device__ inline bf2 bf16_split(float f) {
    unsigned u = __float_as_uint(f);
    unsigned hb = (u + 0x8000u) & 0xFFFF0000u;
    bf2 r;
    r.h = (short)(hb >> 16);
    r.l = bf16_rn(f - __uint_as_float(hb));
    return r;
}

// Block = 256 threads (4 waves), t-tile of 64 for one (b,h); backward s-chunks
// of 64 with stick-breaking suffix-scan between the two MFMA GEMMs.
// QK^T: bf16 hi/lo split (3 MFMAs) -> fp32-accurate scores.
// PV:   att bf16 x V bf16 (att weights sum<=1 -> err ~1e-2 abs, threshold 9.4e-2).
__global__ __launch_bounds__(256, 2) void sb_attn_mfma(const float* __restrict__ qkv,
                                                       float* __restrict__ out) {
    __shared__ alignas(16) short Qhi[TT * QK_STR];
    __shared__ alignas(16) short Qlo[TT * QK_STR];
    __shared__ alignas(16) short Khi[SCH * QK_STR];
    __shared__ alignas(16) short Klo[SCH * QK_STR];
    __shared__ alignas(16) short Vt[DD * VT_STR];      // V^T[d][s], bf16
    __shared__ alignas(16) float Sc[TT * SC_STR];      // scores fp32; att bf16 overlays
    __shared__ float asum[TT];
    __shared__ float Ccar[TT];
    __shared__ int done_cnt;                           // monotonic: rows whose C crossed 30

    const int tid  = threadIdx.x;
    const int w    = tid >> 6;
    const int lane = tid & 63;
    const int m    = lane & 15;       // MFMA row/col-in-tile
    const int q    = lane >> 4;       // MFMA quad
    const int wrow = w * 16;          // this wave's t-stripe [wrow, wrow+16)
    const int g    = tid >> 4;        // staging row group 0..15
    const int li   = tid & 15;        // staging lane-in-group

    const int bh = blockIdx.x >> 5;
    const int h  = bh & (HH - 1);
    const int b  = bh >> 4;
    const int T0 = (blockIdx.x & 31) * TT;

    const float scale = 0.1875f;      // 1.5/sqrt(64)
    const float* qb = qkv + (size_t)b * SSEQ * ROW + h * DD;
    const float* kb = qb + HH * DD;
    const float* vb = qb + 2 * HH * DD;

    // ---- stage Q hi/lo (once). group g -> rows g*4..g*4+3, li -> d = li*4..+3
    #pragma unroll
    for (int rr = 0; rr < 4; ++rr) {
        const int r = g * 4 + rr;
        float4 v4 = *(const float4*)&qb[(size_t)(T0 + r) * ROW + li * 4];
        bf2 sx = bf16_split(v4.x * scale);
        bf2 sy = bf16_split(v4.y * scale);
        bf2 sz = bf16_split(v4.z * scale);
        bf2 sw = bf16_split(v4.w * scale);
        short4v hv = {sx.h, sy.h, sz.h, sw.h};
        short4v lv = {sx.l, sy.l, sz.l, sw.l};
        *(short4v*)&Qhi[r * QK_STR + li * 4] = hv;
        *(short4v*)&Qlo[r * QK_STR + li * 4] = lv;
    }
    if (tid < TT) { asum[tid] = 0.f; Ccar[tid] = 0.f; }
    if (tid == 0) done_cnt = 0;

    floatx4 oac[4] = {{0,0,0,0},{0,0,0,0},{0,0,0,0},{0,0,0,0}};  // 16t x 64d per wave

    int chunk = 0;
    for (int S0 = T0; S0 >= 0; S0 -= SCH, ++chunk) {
        __syncthreads();   // B1: prev PV done (Vt/Khi free); done_cnt visible
        if (chunk > 0 && done_cnt == TT) break;

        // ---- stage K hi/lo
        #pragma unroll
        for (int rr = 0; rr < 4; ++rr) {
            const int r = g * 4 + rr;
            float4 v4 = *(const float4*)&kb[(size_t)(S0 + r) * ROW + li * 4];
            bf2 sx = bf16_split(v4.x);
            bf2 sy = bf16_split(v4.y);
            bf2 sz = bf16_split(v4.z);
            bf2 sw = bf16_split(v4.w);
            short4v hv = {sx.h, sy.h, sz.h, sw.h};
            short4v lv = {sx.l, sy.l, sz.l, sw.l};
            *(short4v*)&Khi[r * QK_STR + li * 4] = hv;
            *(short4v*)&Klo[r * QK_STR + li * 4] = lv;
        }
        // ---- stage V^T (bf16): thread d=lane, wave w covers s in [w*16, w*16+16)
        #pragma unroll
        for (int u = 0; u < 4; ++u) {
            const int s0v = w * 16 + u * 4;
            float a0 = vb[(size_t)(S0 + s0v + 0) * ROW + lane];
            float a1 = vb[(size_t)(S0 + s0v + 1) * ROW + lane];
            float a2 = vb[(size_t)(S0 + s0v + 2) * ROW + lane];
            float a3 = vb[(size_t)(S0 + s0v + 3) * ROW + lane];
            short4v hv = {bf16_rn(a0), bf16_rn(a1), bf16_rn(a2), bf16_rn(a3)};
            *(short4v*)&Vt[lane * VT_STR + s0v] = hv;
        }
        __syncthreads();   // B2: tiles staged

        // ---- QK^T: wave stripe 16t x 64s, 4 tiles, K=64 in 2 ksteps, hi/lo split
        {
            floatx4 acc[4] = {{0,0,0,0},{0,0,0,0},{0,0,0,0},{0,0,0,0}};
            #pragma unroll
            for (int ks = 0; ks < 2; ++ks) {
                const int ko = ks * 32 + q * 8;
                short8 Ah = *(const short8*)&Qhi[(wrow + m) * QK_STR + ko];
                short8 Al = *(const short8*)&Qlo[(wrow + m) * QK_STR + ko];
                #pragma unroll
                for (int n = 0; n < 4; ++n) {
                    short8 Bh = *(const short8*)&Khi[(n * 16 + m) * QK_STR + ko];
                    short8 Bl = *(const short8*)&Klo[(n * 16 + m) * QK_STR + ko];
                    acc[n] = __builtin_amdgcn_mfma_f32_16x16x32_bf16(Ah, Bh, acc[n], 0, 0, 0);
                    acc[n] = __builtin_amdgcn_mfma_f32_16x16x32_bf16(Ah, Bl, acc[n], 0, 0, 0);
                    acc[n] = __builtin_amdgcn_mfma_f32_16x16x32_bf16(Al, Bh, acc[n], 0, 0, 0);
                }
            }
            // C/D layout: col = n*16 + m, row = wrow + q*4 + reg
            #pragma unroll
            for (int n = 0; n < 4; ++n)
                #pragma unroll
                for (int reg = 0; reg < 4; ++reg)
                    Sc[(wrow + q * 4 + reg) * SC_STR + n * 16 + m] = acc[n][reg];
        }

        // ---- suffix scan per row (wave-private rows; lane = s), att -> P (bf16, overlays Sc)
        short* P = (short*)Sc;   // row stride 136 shorts (272 B)
        #pragma unroll
        for (int j = 0; j < 16; ++j) {
            const int tl = wrow + j;
            const int tG = T0 + tl;
            const float x = Sc[tl * SC_STR + lane];
            const bool valid = (S0 + lane) < tG;
            const float sp = valid ? (fmaxf(x, 0.f) + log1pf(__expf(-fabsf(x)))) : 0.f;
            float v = sp;
            #pragma unroll
            for (int off = 1; off < 64; off <<= 1) {
                float ov = __shfl_down(v, off, 64);
                if (lane + off < 64) v += ov;
            }
            const float rev = v - sp;             // sum over s' > lane in chunk
            const float ctot = __shfl(v, 0, 64);  // chunk softplus total
            const float C = Ccar[tl];
            const float att = valid ? __expf(x - sp - rev - C) : 0.f;
            P[tl * 136 + lane] = bf16_rn(att);
            float a = att;
            #pragma unroll
            for (int off = 32; off > 0; off >>= 1) a += __shfl_xor(a, off, 64);
            if (lane == 0) {
                asum[tl] += a;
                const float Cn = C + ctot;
                Ccar[tl] = Cn;
                if (C <= 30.f && Cn > 30.f) atomicAdd(&done_cnt, 1);
            }
        }

        // ---- PV: att (A, bf16) x V^T (B, bf16) -> accumulate oac
        #pragma unroll
        for (int ks = 0; ks < 2; ++ks) {
            const int ko = ks * 32 + q * 8;
            short8 Ap = *(const short8*)&P[(wrow + m) * 136 + ko];
            #pragma unroll
            for (int n = 0; n < 4; ++n) {
                const short* vp = &Vt[(n * 16 + m) * VT_STR + ko];
                short4v b0 = *(const short4v*)vp;
                short4v b1 = *(const short4v*)(vp + 4);
                short8 Bv = {b0.x, b0.y, b0.z, b0.w, b1.x, b1.y, b1.z, b1.w};
                oac[n] = __builtin_amdgcn_mfma_f32_16x16x32_bf16(Ap, Bv, oac[n], 0, 0, 0);
            }
        }
    }

    // ---- epilogue: out = oac + rem * v_t
    #pragma unroll
    for (int n = 0; n < 4; ++n) {
        #pragma unroll
        for (int reg = 0; reg < 4; ++reg) {
            const int tl = wrow + q * 4 + reg;
            const int tG = T0 + tl;
            const int dc = n * 16 + m;
            const float rem = 1.f - asum[tl];
            const float vt = vb[(size_t)tG * ROW + dc];
            out[(((size_t)b * SSEQ + tG) * HH + h) * DD + dc] = fmaf(rem, vt, oac[n][reg]);
        }
    }
}

extern "C" void kernel_launch(void* const* d_in, const int* in_sizes, int n_in,
                              void* d_out, int out_size, void* d_ws, size_t ws_size,
                              hipStream_t stream) {
    const float* qkv = (const float*)d_in[0];
    float* out = (float*)d_out;
    const int blocks = BB * HH * (SSEQ / TT);   // 1024
    sb_attn_mfma<<<blocks, 256, 0, stream>>>(qkv, out);
}

// Round 8
// 100.103 us; speedup vs baseline: 5.3387x; 1.4013x over previous
//
#include <hip/hip_runtime.h>
#include <math.h>
#include <cstddef>

#define BB 2
#define SSEQ 2048
#define HH 16
#define DD 64
#define ROW 3072              // floats per (b,s) row = 3*H*D
#define TT 64                 // t-tile per block
#define SCH 64                // s-chunk

#define QK_STR 72             // bf16 elems/row for Q/K tiles (144 B rows, 16B-aligned)
#define VT_STR 68             // bf16 elems/row for V^T
#define SP_STR 76             // uints/row for packed sp hi|lo (304 B rows, 16B-aligned)

typedef __attribute__((ext_vector_type(8))) short short8;
typedef __attribute__((ext_vector_type(4))) short short4v;
typedef __attribute__((ext_vector_type(4))) float floatx4;
typedef __attribute__((ext_vector_type(4))) unsigned int uintx4;

__device__ inline short bf16_rn(float f) {
    unsigned u = __float_as_uint(f);
    return (short)((u + 0x8000u) >> 16);
}
struct bf2 { short h, l; };
__device__ inline bf2 bf16_split(float f) {
    unsigned u = __float_as_uint(f);
    unsigned hb = (u + 0x8000u) & 0xFFFF0000u;
    bf2 r;
    r.h = (short)(hb >> 16);
    r.l = bf16_rn(f - __uint_as_float(hb));
    return r;
}

// Stick-breaking attention, all-MFMA datapath:
//   QK^T (bf16 hi/lo, 24 MFMA) -> sp = softplus in regs -> sp-tile LDS round trip
//   -> suffix-scan rev = sp * M via MFMA with CONSTANT register B-frags (16 MFMA)
//   -> running C via B=ones MFMA (4) -> att = exp(x-sp-rev-C) in regs
//   -> att bf16 -> PV MFMA (8) + row-sum via B=ones (2).
// No shuffles, no atomics; 2 barriers/chunk (K/V staging only); sp/att stripes
// are wave-private (no barrier).
__global__ __launch_bounds__(256, 2) void sb_attn_mfma2(const float* __restrict__ qkv,
                                                        float* __restrict__ out) {
    __shared__ alignas(16) short Qhi[TT * QK_STR];
    __shared__ alignas(16) short Qlo[TT * QK_STR];
    __shared__ alignas(16) short Khi[SCH * QK_STR];
    __shared__ alignas(16) short Klo[SCH * QK_STR];
    __shared__ alignas(16) short Vt[DD * VT_STR];        // V^T[d][s], bf16
    __shared__ alignas(16) unsigned int spP[TT * SP_STR]; // packed sp hi<<16|lo; att overlays
    __shared__ int wdone[4];

    const int tid  = threadIdx.x;
    const int w    = tid >> 6;
    const int lane = tid & 63;
    const int m    = lane & 15;
    const int q    = lane >> 4;
    const int wrow = w * 16;
    const int g    = tid >> 4;
    const int li   = tid & 15;

    const int bh = blockIdx.x >> 5;
    const int h  = bh & (HH - 1);
    const int b  = bh >> 4;
    const int T0 = (blockIdx.x & 31) * TT;

    const float scale = 0.1875f;   // 1.5/sqrt(64)
    const float* qb = qkv + (size_t)b * SSEQ * ROW + h * DD;
    const float* kb = qb + HH * DD;
    const float* vb = qb + 2 * HH * DD;

    // ---- stage Q hi/lo (once)
    #pragma unroll
    for (int rr = 0; rr < 4; ++rr) {
        const int r = g * 4 + rr;
        float4 v4 = *(const float4*)&qb[(size_t)(T0 + r) * ROW + li * 4];
        bf2 sx = bf16_split(v4.x * scale);
        bf2 sy = bf16_split(v4.y * scale);
        bf2 sz = bf16_split(v4.z * scale);
        bf2 sw = bf16_split(v4.w * scale);
        short4v hv = {sx.h, sy.h, sz.h, sw.h};
        short4v lv = {sx.l, sy.l, sz.l, sw.l};
        *(short4v*)&Qhi[r * QK_STR + li * 4] = hv;
        *(short4v*)&Qlo[r * QK_STR + li * 4] = lv;
    }
    if (tid < 4) wdone[tid] = 0;

    // ---- constant B-frags in registers: M (strict upper triangular) and ones
    const short ONE = (short)0x3F80;
    short8 onesf;
    #pragma unroll
    for (int j = 0; j < 8; ++j) onesf[j] = ONE;
    short8 Mfrag[2][4];
    #pragma unroll
    for (int ks = 0; ks < 2; ++ks)
        #pragma unroll
        for (int n = 0; n < 4; ++n)
            #pragma unroll
            for (int j = 0; j < 8; ++j)
                Mfrag[ks][n][j] = ((ks * 32 + q * 8 + j) > (n * 16 + m)) ? ONE : (short)0;

    floatx4 oac[4] = {{0,0,0,0},{0,0,0,0},{0,0,0,0},{0,0,0,0}};
    floatx4 ctotAcc = {0,0,0,0};   // running C per row (replicated over cols)
    floatx4 asumAcc = {0,0,0,0};   // running att row-sum

    short* attA = (short*)&spP[wrow * SP_STR];  // wave-private att stripe, stride 72 shorts

    int chunk = 0;
    for (int S0 = T0; S0 >= 0; S0 -= SCH, ++chunk) {
        __syncthreads();   // B1: prev PV done with Vt/K; wdone visible
        if (chunk > 0 && (wdone[0] & wdone[1] & wdone[2] & wdone[3])) break;

        // ---- stage K hi/lo
        #pragma unroll
        for (int rr = 0; rr < 4; ++rr) {
            const int r = g * 4 + rr;
            float4 v4 = *(const float4*)&kb[(size_t)(S0 + r) * ROW + li * 4];
            bf2 sx = bf16_split(v4.x);
            bf2 sy = bf16_split(v4.y);
            bf2 sz = bf16_split(v4.z);
            bf2 sw = bf16_split(v4.w);
            short4v hv = {sx.h, sy.h, sz.h, sw.h};
            short4v lv = {sx.l, sy.l, sz.l, sw.l};
            *(short4v*)&Khi[r * QK_STR + li * 4] = hv;
            *(short4v*)&Klo[r * QK_STR + li * 4] = lv;
        }
        // ---- stage V^T bf16
        #pragma unroll
        for (int u = 0; u < 4; ++u) {
            const int s0v = w * 16 + u * 4;
            float a0 = vb[(size_t)(S0 + s0v + 0) * ROW + lane];
            float a1 = vb[(size_t)(S0 + s0v + 1) * ROW + lane];
            float a2 = vb[(size_t)(S0 + s0v + 2) * ROW + lane];
            float a3 = vb[(size_t)(S0 + s0v + 3) * ROW + lane];
            short4v hv = {bf16_rn(a0), bf16_rn(a1), bf16_rn(a2), bf16_rn(a3)};
            *(short4v*)&Vt[lane * VT_STR + s0v] = hv;
        }
        __syncthreads();   // B2: tiles staged

        // ---- QK^T (hi/lo split, 24 MFMA)
        floatx4 acc[4] = {{0,0,0,0},{0,0,0,0},{0,0,0,0},{0,0,0,0}};
        #pragma unroll
        for (int ks = 0; ks < 2; ++ks) {
            const int ko = ks * 32 + q * 8;
            short8 Ah = *(const short8*)&Qhi[(wrow + m) * QK_STR + ko];
            short8 Al = *(const short8*)&Qlo[(wrow + m) * QK_STR + ko];
            #pragma unroll
            for (int n = 0; n < 4; ++n) {
                short8 Bh = *(const short8*)&Khi[(n * 16 + m) * QK_STR + ko];
                short8 Bl = *(const short8*)&Klo[(n * 16 + m) * QK_STR + ko];
                acc[n] = __builtin_amdgcn_mfma_f32_16x16x32_bf16(Ah, Bh, acc[n], 0, 0, 0);
                acc[n] = __builtin_amdgcn_mfma_f32_16x16x32_bf16(Ah, Bl, acc[n], 0, 0, 0);
                acc[n] = __builtin_amdgcn_mfma_f32_16x16x32_bf16(Al, Bh, acc[n], 0, 0, 0);
            }
        }

        // ---- sp = softplus(x) masked, hi/lo packed -> LDS (wave-private, C-layout addr)
        float spv[4][4];
        #pragma unroll
        for (int n = 0; n < 4; ++n) {
            #pragma unroll
            for (int reg = 0; reg < 4; ++reg) {
                const int row = wrow + q * 4 + reg;
                const bool valid = (S0 + n * 16 + m) < (T0 + row);
                const float x = acc[n][reg];
                const float s = valid ? __logf(1.f + __expf(x)) : 0.f;
                spv[n][reg] = s;
                bf2 sl = bf16_split(s);
                spP[row * SP_STR + n * 16 + m] =
                    ((unsigned)(unsigned short)sl.h << 16) | (unsigned)(unsigned short)sl.l;
            }
        }

        // ---- read sp A-frags (row = wrow+m), unpack hi/lo
        short8 SAh[2], SAl[2];
        #pragma unroll
        for (int ks = 0; ks < 2; ++ks) {
            const unsigned int* pp = &spP[(wrow + m) * SP_STR + ks * 32 + q * 8];
            uintx4 r0 = *(const uintx4*)pp;
            uintx4 r1 = *(const uintx4*)(pp + 4);
            unsigned pv[8] = {r0.x, r0.y, r0.z, r0.w, r1.x, r1.y, r1.z, r1.w};
            #pragma unroll
            for (int j = 0; j < 8; ++j) {
                SAh[ks][j] = (short)(pv[j] >> 16);
                SAl[ks][j] = (short)(pv[j] & 0xFFFFu);
            }
        }

        // ---- snapshot carry BEFORE accumulating this chunk's totals
        const float Cold[4] = {ctotAcc[0], ctotAcc[1], ctotAcc[2], ctotAcc[3]};

        // ---- scan MFMAs: rev = sp * M  (16) ; ctot += sp * ones (4)
        floatx4 rev[4] = {{0,0,0,0},{0,0,0,0},{0,0,0,0},{0,0,0,0}};
        #pragma unroll
        for (int ks = 0; ks < 2; ++ks) {
            #pragma unroll
            for (int n = 0; n < 4; ++n) {
                rev[n] = __builtin_amdgcn_mfma_f32_16x16x32_bf16(SAh[ks], Mfrag[ks][n], rev[n], 0, 0, 0);
                rev[n] = __builtin_amdgcn_mfma_f32_16x16x32_bf16(SAl[ks], Mfrag[ks][n], rev[n], 0, 0, 0);
            }
            ctotAcc = __builtin_amdgcn_mfma_f32_16x16x32_bf16(SAh[ks], onesf, ctotAcc, 0, 0, 0);
            ctotAcc = __builtin_amdgcn_mfma_f32_16x16x32_bf16(SAl[ks], onesf, ctotAcc, 0, 0, 0);
        }

        // ---- att = exp(x - sp - rev - C) in regs -> bf16 stripe (overlays spP stripe)
        #pragma unroll
        for (int n = 0; n < 4; ++n) {
            #pragma unroll
            for (int reg = 0; reg < 4; ++reg) {
                const int row = q * 4 + reg;
                const bool valid = (S0 + n * 16 + m) < (T0 + wrow + row);
                const float y = acc[n][reg] - spv[n][reg] - rev[n][reg] - Cold[reg];
                const float a = valid ? __expf(y) : 0.f;
                attA[row * 72 + n * 16 + m] = bf16_rn(a);
            }
        }

        // ---- PV (8 MFMA) + att row-sums via ones (2 MFMA)
        #pragma unroll
        for (int ks = 0; ks < 2; ++ks) {
            const int ko = ks * 32 + q * 8;
            short8 Ap = *(const short8*)&attA[m * 72 + ko];
            asumAcc = __builtin_amdgcn_mfma_f32_16x16x32_bf16(Ap, onesf, asumAcc, 0, 0, 0);
            #pragma unroll
            for (int n = 0; n < 4; ++n) {
                const short* vp = &Vt[(n * 16 + m) * VT_STR + ko];
                short4v b0 = *(const short4v*)vp;
                short4v b1 = *(const short4v*)(vp + 4);
                short8 Bv = {b0.x, b0.y, b0.z, b0.w, b1.x, b1.y, b1.z, b1.w};
                oac[n] = __builtin_amdgcn_mfma_f32_16x16x32_bf16(Ap, Bv, oac[n], 0, 0, 0);
            }
        }

        // ---- done flag (monotone; C only grows)
        const bool myd = (ctotAcc[0] > 30.f) && (ctotAcc[1] > 30.f) &&
                         (ctotAcc[2] > 30.f) && (ctotAcc[3] > 30.f);
        const int wd = __all((int)myd);
        if (lane == 0) wdone[w] = wd;
    }

    // ---- epilogue: out = oac + (1 - asum) * v_t
    #pragma unroll
    for (int n = 0; n < 4; ++n) {
        #pragma unroll
        for (int reg = 0; reg < 4; ++reg) {
            const int tl = wrow + q * 4 + reg;
            const int tG = T0 + tl;
            const int dc = n * 16 + m;
            const float rem = 1.f - asumAcc[reg];
            const float vt = vb[(size_t)tG * ROW + dc];
            out[(((size_t)b * SSEQ + tG) * HH + h) * DD + dc] = fmaf(rem, vt, oac[n][reg]);
        }
    }
}

extern "C" void kernel_launch(void* const* d_in, const int* in_sizes, int n_in,
                              void* d_out, int out_size, void* d_ws, size_t ws_size,
                              hipStream_t stream) {
    const float* qkv = (const float*)d_in[0];
    float* out = (float*)d_out;
    const int blocks = BB * HH * (SSEQ / TT);   // 1024
    sb_attn_mfma2<<<blocks, 256, 0, stream>>>(qkv, out);
}